// Round 3
// 598.978 us; speedup vs baseline: 1.0696x; 1.0696x over previous
//
#include <hip/hip_runtime.h>
#include <cstdint>
#include <cstddef>

typedef unsigned int  uint_t;
typedef unsigned short ushort_t;

// ---- shapes (fixed for this problem) ----
constexpr int B_  = 64;
constexpr int S_  = 128;
constexpr int D_  = 100;   // triple embedding dim
constexpr int E_  = 300;   // word embedding dim
constexpr int H_  = 256;   // hidden
constexpr int KIN = 512;   // LSTM input 500 padded to 512 for MFMA K
constexpr int NG  = 1024;  // 4*H gates
constexpr int M_  = B_ * S_;  // 8192

// K3 weight split: per gate row, each thread owns 64 f16x2 words (half of K);
// RW in VGPRs, LW in LDS.
constexpr int RW = 48;
constexpr int LW = 16;   // 4 chunks of 4 words

// ---- workspace layout (bytes) ----
constexpr size_t OFF_WT   = 0;                                  // W_ent^T packed f16x2 [100 kp][100 d] (40000 B)
constexpr size_t OFF_FLAG = 40000;                              // int: 1 if inputs are fp32, 0 if bf16
constexpr size_t OFF_WIH  = 40960;                              // W_ih padded bf16 [1024][512]
constexpr size_t OFF_WHH  = OFF_WIH + (size_t)NG * KIN * 2;     // W_hh as f16x2, [128][1024] u32
constexpr size_t OFF_TIN  = OFF_WHH + (size_t)128 * NG * 4;     // t_in bf16 [8192][512]
constexpr size_t OFF_XG   = OFF_TIN + (size_t)M_ * KIN * 2;     // xg f32 [8192][1024]
constexpr size_t OFF_HOUT = OFF_XG + (size_t)M_ * NG * 4;       // h f32 [8192][256]
// total ~50 MB

// ---- helpers ----
__device__ __forceinline__ float b2f(ushort_t u) {
  union { uint_t u; float f; } v; v.u = ((uint_t)u) << 16; return v.f;
}
__device__ __forceinline__ float blo(uint_t u) {
  union { uint_t u; float f; } v; v.u = u << 16; return v.f;
}
__device__ __forceinline__ float bhi(uint_t u) {
  union { uint_t u; float f; } v; v.u = u & 0xffff0000u; return v.f;
}
__device__ __forceinline__ ushort_t f2b(float f) {  // RNE float->bf16
  union { float f; uint_t u; } v; v.f = f;
  uint_t r = (v.u + 0x7fffu + ((v.u >> 16) & 1u)) >> 16;
  return (ushort_t)r;
}
__device__ __forceinline__ ushort_t f16bits(float f) {
  _Float16 h = (_Float16)f;
  union { _Float16 h; ushort_t u; } v; v.h = h; return v.u;
}
__device__ __forceinline__ uint_t pk16(float a, float b) {
  return (uint_t)f16bits(a) | ((uint_t)f16bits(b) << 16);
}
__device__ __forceinline__ float fast_tanh(float x) {
  float e = __expf(2.f * x);
  return 1.f - 2.f / (e + 1.f);
}
__device__ __forceinline__ float sigm(float x) {
  return 1.f / (1.f + __expf(-x));
}
// dtype-flexible load of an external "float" tensor
__device__ __forceinline__ float ldv(const void* p, size_t i, int f32) {
  return f32 ? ((const float*)p)[i] : b2f(((const ushort_t*)p)[i]);
}

#if defined(__has_builtin)
#if __has_builtin(__builtin_amdgcn_fdot2)
#define HAVE_FDOT2 1
#endif
#endif

typedef _Float16 half2v __attribute__((ext_vector_type(2)));

__device__ __forceinline__ float dot2(uint_t w, uint_t h, float acc) {
#ifdef HAVE_FDOT2
  union { uint_t u; half2v v; } a, b; a.u = w; b.u = h;
  return __builtin_amdgcn_fdot2(a.v, b.v, acc, false);
#else
  union { uint_t u; _Float16 h[2]; } a, b; a.u = w; b.u = h;
  acc += (float)a.h[0] * (float)b.h[0];
  acc += (float)a.h[1] * (float)b.h[1];
  return acc;
#endif
}

// =====================================================================
// K_detect: decide whether external float tensors are fp32 or bf16.
// =====================================================================
__global__ __launch_bounds__(64) void k_detect(const uint_t* __restrict__ emb_w,
                                               char* __restrict__ ws)
{
  int tid = threadIdx.x;
  int hits = 0;
  for (int i = 0; i < 8; ++i) {
    uint_t w = emb_w[i * 64 + tid];
    uint_t e = (w >> 7) & 0xffu;   // exponent field of lo-ushort-as-bf16
    hits += (e >= 140) ? 1 : 0;
  }
  for (int off = 32; off > 0; off >>= 1) hits += __shfl_down(hits, off);
  if (tid == 0) *(int*)(ws + OFF_FLAG) = (hits >= 32) ? 1 : 0;
}

// =====================================================================
// K0: weight prep. Wt = W_ent^T packed f16x2 (K-pairs); W_ih padded
// K 500->512 (bf16); W_hh -> f16x2 packed, transposed to [kpair][row].
// =====================================================================
__global__ __launch_bounds__(256) void k0_prep(
    const void* __restrict__ W_ent, const void* __restrict__ W_ih,
    const void* __restrict__ W_hh, char* __restrict__ ws)
{
  const int f32 = *(const int*)(ws + OFF_FLAG);
  int id = blockIdx.x * 256 + threadIdx.x;
  uint_t*   Wt = (uint_t*)(ws + OFF_WT);
  ushort_t* Wp = (ushort_t*)(ws + OFF_WIH);
  uint_t*   WT = (uint_t*)(ws + OFF_WHH);
  if (id < 10000) {
    // Wt[kp*100+d] = pack(f16(W_ent[d][2kp]), f16(W_ent[d][2kp+1]))
    int kp = id / 100, d = id % 100;
    float a = ldv(W_ent, (size_t)d * 200 + 2 * kp,     f32);
    float b = ldv(W_ent, (size_t)d * 200 + 2 * kp + 1, f32);
    Wt[id] = pk16(a, b);
  } else if (id >= 20000 && id < 20000 + NG * KIN) {
    int i = id - 20000;
    int n = i >> 9, k = i & 511;
    Wp[i] = (k < 500) ? f2b(ldv(W_ih, (size_t)n * 500 + k, f32)) : (ushort_t)0;
  } else if (id >= 20000 + NG * KIN && id < 20000 + NG * KIN + 128 * NG) {
    int i = id - 20000 - NG * KIN;
    int kk = i >> 10, j = i & 1023;
    ushort_t lo = f16bits(ldv(W_hh, (size_t)j * 256 + 2 * kk,     f32));
    ushort_t hi = f16bits(ldv(W_hh, (size_t)j * 256 + 2 * kk + 1, f32));
    WT[kk * 1024 + j] = (uint_t)lo | ((uint_t)hi << 16);
  }
}

// =====================================================================
// K1: triple graph attention per (b,s); writes t_in bf16 [m][512].
// Hot loop in packed f16x2 dot2: 100 K-pair iters x (1 uint4 + 2 uint
// LDS reads + 8 v_dot2) vs the old 200 x (8 scalar FMA + bf16 unpacks).
// ht staged packed (htp, 4 KB) -> LDS/block 48.2 KB, 3 blocks/CU.
// =====================================================================
__global__ __launch_bounds__(128) void k1_graph(
    const int* __restrict__ inputs, const int* __restrict__ triples,
    const int* __restrict__ id2, const void* __restrict__ emb,
    const void* __restrict__ ent, const void* __restrict__ rel,
    char* __restrict__ ws)
{
  __shared__ __align__(16) uint_t Wl2[10000];   // packed f16x2 [kp][d], 40000 B
  __shared__ uint_t htp[10][100];               // packed f16x2 (ht[2kp], ht[2kp+1])
  __shared__ float er_l[10][100];
  __shared__ float e_l[10];
  __shared__ float alpha_l[10];
  __shared__ int   trip_l[30];
  __shared__ int   vflag;

  const int tid = threadIdx.x;
  const int m   = blockIdx.x;  // b*128+s
  const int f32 = *(const int*)(ws + OFF_FLAG);
  ushort_t* tin = (ushort_t*)(ws + OFF_TIN);

  if (tid < 30) trip_l[tid] = triples[(size_t)m * 30 + tid];
  if (tid == 0) vflag = 0;
  if (tid < 10) e_l[tid] = 0.f;
  __syncthreads();
  if (tid < 10 && id2[(size_t)m * 10 + tid] != -1) atomicOr(&vflag, 1);

  {
    const uint4* src = (const uint4*)(ws + OFF_WT);
    uint4* dst = (uint4*)Wl2;
    for (int i = tid; i < 2500; i += 128) dst[i] = src[i];
  }
  // gather ht rows, pack to f16x2 pairs
  for (int i = tid; i < 1000; i += 128) {
    int t = i / 100, kp = i % 100;
    int row = trip_l[t * 3 + (kp < 50 ? 0 : 1)];
    int off = (kp < 50) ? 2 * kp : 2 * (kp - 50);
    float x0, x1;
    if (f32) {
      float2 v = *(const float2*)((const float*)ent + (size_t)row * 100 + off);
      x0 = v.x; x1 = v.y;
    } else {
      uint_t u = *(const uint_t*)((const ushort_t*)ent + (size_t)row * 100 + off);
      x0 = blo(u); x1 = bhi(u);
    }
    htp[t][kp] = pk16(x0, x1);
  }
  for (int i = tid; i < 1000; i += 128) {
    int t = i / 100, d = i % 100;
    er_l[t][d] = ldv(rel, (size_t)trip_l[t * 3 + 2] * 100 + d, f32);
  }
  {
    int w = inputs[m];
    for (int c = tid; c < 300; c += 128)
      tin[(size_t)m * KIN + c] = f2b(ldv(emb, (size_t)w * E_ + c, f32));
    if (tid < 12) tin[(size_t)m * KIN + 500 + tid] = 0;
  }
  __syncthreads();

  if (tid < 125) {
    int t2 = tid / 25, d4 = tid % 25;
    int t0 = 2 * t2, t1 = t0 + 1;
    const uint_t* h0p = htp[t0];
    const uint_t* h1p = htp[t1];
    float a00 = 0, a01 = 0, a02 = 0, a03 = 0;
    float a10 = 0, a11 = 0, a12 = 0, a13 = 0;
    for (int kp = 0; kp < 100; ++kp) {
      uint4 wv = *(const uint4*)&Wl2[kp * 100 + 4 * d4];  // 4 d-columns at this K-pair
      uint_t hp0 = h0p[kp], hp1 = h1p[kp];
      a00 = dot2(wv.x, hp0, a00); a01 = dot2(wv.y, hp0, a01);
      a02 = dot2(wv.z, hp0, a02); a03 = dot2(wv.w, hp0, a03);
      a10 = dot2(wv.x, hp1, a10); a11 = dot2(wv.y, hp1, a11);
      a12 = dot2(wv.z, hp1, a12); a13 = dot2(wv.w, hp1, a13);
    }
    int d = 4 * d4;
    float s0 = fast_tanh(a00) * er_l[t0][d]     + fast_tanh(a01) * er_l[t0][d + 1]
             + fast_tanh(a02) * er_l[t0][d + 2] + fast_tanh(a03) * er_l[t0][d + 3];
    float s1 = fast_tanh(a10) * er_l[t1][d]     + fast_tanh(a11) * er_l[t1][d + 1]
             + fast_tanh(a12) * er_l[t1][d + 2] + fast_tanh(a13) * er_l[t1][d + 3];
    atomicAdd(&e_l[t0], s0);
    atomicAdd(&e_l[t1], s1);
  }
  __syncthreads();
  if (tid == 0) {
    float mx = e_l[0];
    for (int t = 1; t < 10; ++t) mx = fmaxf(mx, e_l[t]);
    float s = 0.f;
    for (int t = 0; t < 10; ++t) { float v = __expf(e_l[t] - mx); alpha_l[t] = v; s += v; }
    float inv = 1.f / s;
    for (int t = 0; t < 10; ++t) alpha_l[t] *= inv;
  }
  __syncthreads();
  for (int kp = tid; kp < 100; kp += 128) {
    float g0 = 0.f, g1 = 0.f;
#pragma unroll
    for (int t = 0; t < 10; ++t) {
      union { uint_t u; _Float16 h[2]; } v; v.u = htp[t][kp];
      g0 += alpha_l[t] * (float)v.h[0];
      g1 += alpha_l[t] * (float)v.h[1];
    }
    if (!vflag) { g0 = 0.f; g1 = 0.f; }
    tin[(size_t)m * KIN + 300 + 2 * kp]     = f2b(g0);
    tin[(size_t)m * KIN + 300 + 2 * kp + 1] = f2b(g1);
  }
}

// =====================================================================
// K2: xg = t_in @ W_ih^T + b.  MFMA 16x16x32 bf16, 128x128 tiles, BK=32.
// =====================================================================
typedef __attribute__((ext_vector_type(8))) short short8;
typedef __attribute__((ext_vector_type(4))) float f32x4;

__global__ __launch_bounds__(256) void k2_xg(
    const void* __restrict__ bl, char* __restrict__ ws)
{
  __shared__ __align__(16) ushort_t As[128 * 32];
  __shared__ __align__(16) ushort_t Bs[128 * 32];
  const ushort_t* A  = (const ushort_t*)(ws + OFF_TIN);
  const ushort_t* Bw = (const ushort_t*)(ws + OFF_WIH);
  float* xg = (float*)(ws + OFF_XG);
  const int f32 = *(const int*)(ws + OFF_FLAG);

  const int tid = threadIdx.x;
  const int m0 = blockIdx.x * 128;
  const int n0 = blockIdx.y * 128;
  const int lane = tid & 63, wv = tid >> 6;
  const int wm = wv & 1, wn = wv >> 1;
  const int g = lane >> 4, r = lane & 15;

  f32x4 acc[4][4] = {};

  for (int ks = 0; ks < 16; ++ks) {
    const int k0 = ks * 32;
    {
      int c0 = tid, c1 = tid + 256;
      uint4 a0 = *(const uint4*)(A  + (size_t)(m0 + (c0 >> 2)) * KIN + k0 + ((c0 & 3) << 3));
      uint4 a1 = *(const uint4*)(A  + (size_t)(m0 + (c1 >> 2)) * KIN + k0 + ((c1 & 3) << 3));
      uint4 b0 = *(const uint4*)(Bw + (size_t)(n0 + (c0 >> 2)) * KIN + k0 + ((c0 & 3) << 3));
      uint4 b1 = *(const uint4*)(Bw + (size_t)(n0 + (c1 >> 2)) * KIN + k0 + ((c1 & 3) << 3));
      ((uint4*)As)[c0] = a0; ((uint4*)As)[c1] = a1;
      ((uint4*)Bs)[c0] = b0; ((uint4*)Bs)[c1] = b1;
    }
    __syncthreads();
    short8 av[4], bv[4];
#pragma unroll
    for (int i = 0; i < 4; ++i)
      av[i] = *(const short8*)&As[(wm * 64 + i * 16 + r) * 32 + g * 8];
#pragma unroll
    for (int j = 0; j < 4; ++j)
      bv[j] = *(const short8*)&Bs[(wn * 64 + j * 16 + r) * 32 + g * 8];
#pragma unroll
    for (int i = 0; i < 4; ++i)
#pragma unroll
      for (int j = 0; j < 4; ++j)
        acc[i][j] = __builtin_amdgcn_mfma_f32_16x16x32_bf16(av[i], bv[j], acc[i][j], 0, 0, 0);
    __syncthreads();
  }
#pragma unroll
  for (int j = 0; j < 4; ++j) {
    int n = n0 + wn * 64 + j * 16 + r;
    float bias = ldv(bl, n, f32);
#pragma unroll
    for (int i = 0; i < 4; ++i) {
      int mrow = m0 + wm * 64 + i * 16 + g * 4;
#pragma unroll
      for (int rr = 0; rr < 4; ++rr)
        xg[(size_t)(mrow + rr) * NG + n] = acc[i][j][rr] + bias;
    }
  }
}

// =====================================================================
// K3: recurrent LSTM, hybrid reg+LDS weights, occupancy pinned.
// 64 blocks (1/batch) x 512 threads (8 waves = 2/SIMD, pinned via
// amdgpu_waves_per_eu(2,2) -> 256-VGPR budget the allocator can use).
// Thread-pair (lanes 2j,2j+1) owns hidden unit u=tid>>1, all 4 gate
// rows {u,u+256,u+512,u+768}; K split in halves across the pair
// (half=tid&1 -> words [64*half, 64*half+64)). Per row: RW=48 words in
// VGPRs (4x48=192 regs), LW=16 words in LDS ([chunk][tid] uint4,
// conflict-free b128). h double-buffered in LDS as f16x2; one barrier
// per step; xg software-prefetched one step ahead.
// =====================================================================
__global__ __attribute__((amdgpu_waves_per_eu(2, 2))) __launch_bounds__(512)
void k3_lstm(char* __restrict__ ws)
{
  extern __shared__ __align__(16) char smem[];
  uint4*    ldsw = (uint4*)smem;                          // [16][512] uint4 = 128 KB
  ushort_t* hbuf = (ushort_t*)(smem + 16 * 512 * 16);     // [2][256] f16

  const int tid  = threadIdx.x;
  const int b    = blockIdx.x;
  const int u    = tid >> 1;          // hidden unit 0..255
  const int half = tid & 1;           // K-half
  const int kbase = half * 64;        // first f16x2 word of my K-half

  const uint_t* WT = (const uint_t*)(ws + OFF_WHH);  // [kpair][1024]
  const float* xg = (const float*)(ws + OFF_XG);
  float* hout = (float*)(ws + OFF_HOUT);

  const int row0 = u, row1 = u + 256, row2 = u + 512, row3 = u + 768;

  // ---- register-resident weights: 4 rows x RW words
  uint_t w0[RW], w1[RW], w2[RW], w3[RW];
#pragma unroll
  for (int q = 0; q < RW; ++q) {
    w0[q] = WT[(size_t)(kbase + q) * 1024 + row0];
    w1[q] = WT[(size_t)(kbase + q) * 1024 + row1];
    w2[q] = WT[(size_t)(kbase + q) * 1024 + row2];
    w3[q] = WT[(size_t)(kbase + q) * 1024 + row3];
  }
  // ---- LDS-resident weights: chunk c=i*4+p holds words kbase+RW+4p..+3 of row i
  {
    const int rows[4] = { row0, row1, row2, row3 };
#pragma unroll
    for (int i = 0; i < 4; ++i)
#pragma unroll
      for (int p = 0; p < 4; ++p) {
        uint4 v;
        v.x = WT[(size_t)(kbase + RW + 4 * p + 0) * 1024 + rows[i]];
        v.y = WT[(size_t)(kbase + RW + 4 * p + 1) * 1024 + rows[i]];
        v.z = WT[(size_t)(kbase + RW + 4 * p + 2) * 1024 + rows[i]];
        v.w = WT[(size_t)(kbase + RW + 4 * p + 3) * 1024 + rows[i]];
        ldsw[(i * 4 + p) * 512 + tid] = v;
      }
  }
  hbuf[tid] = 0;   // zero both h buffers (512 f16 entries)
  float c = 0.f;
  __syncthreads();

  const int bm = b * S_;
  // prefetch xg for t=0
  const float* xp0 = xg + (size_t)bm * NG;
  float xn0 = xp0[row0], xn1 = xp0[row1], xn2 = xp0[row2], xn3 = xp0[row3];

  for (int t = 0; t < S_; ++t) {
    const int cur = t & 1;
    float x0 = xn0, x1 = xn1, x2 = xn2, x3 = xn3;
    if (t + 1 < S_) {   // prefetch next step's gate inputs
      const float* xq = xg + (size_t)(bm + t + 1) * NG;
      xn0 = xq[row0]; xn1 = xq[row1]; xn2 = xq[row2]; xn3 = xq[row3];
    }
    const uint_t* hb = (const uint_t*)(hbuf + cur * 256);
    float a0 = 0.f, a1 = 0.f, a2 = 0.f, a3 = 0.f;
    // register part: 12 uint4 h-reads x 16 dot2
#pragma unroll
    for (int qq = 0; qq < RW / 4; ++qq) {
      uint4 hv = *(const uint4*)&hb[kbase + 4 * qq];
      a0 = dot2(w0[4 * qq], hv.x, a0); a0 = dot2(w0[4 * qq + 1], hv.y, a0);
      a0 = dot2(w0[4 * qq + 2], hv.z, a0); a0 = dot2(w0[4 * qq + 3], hv.w, a0);
      a1 = dot2(w1[4 * qq], hv.x, a1); a1 = dot2(w1[4 * qq + 1], hv.y, a1);
      a1 = dot2(w1[4 * qq + 2], hv.z, a1); a1 = dot2(w1[4 * qq + 3], hv.w, a1);
      a2 = dot2(w2[4 * qq], hv.x, a2); a2 = dot2(w2[4 * qq + 1], hv.y, a2);
      a2 = dot2(w2[4 * qq + 2], hv.z, a2); a2 = dot2(w2[4 * qq + 3], hv.w, a2);
      a3 = dot2(w3[4 * qq], hv.x, a3); a3 = dot2(w3[4 * qq + 1], hv.y, a3);
      a3 = dot2(w3[4 * qq + 2], hv.z, a3); a3 = dot2(w3[4 * qq + 3], hv.w, a3);
    }
    // LDS part: words kbase+RW .. kbase+63
#pragma unroll
    for (int p = 0; p < 4; ++p) {
      uint4 hv = *(const uint4*)&hb[kbase + RW + 4 * p];
      uint4 v0 = ldsw[(0 * 4 + p) * 512 + tid];
      uint4 v1 = ldsw[(1 * 4 + p) * 512 + tid];
      uint4 v2 = ldsw[(2 * 4 + p) * 512 + tid];
      uint4 v3 = ldsw[(3 * 4 + p) * 512 + tid];
      a0 = dot2(v0.x, hv.x, a0); a0 = dot2(v0.y, hv.y, a0);
      a0 = dot2(v0.z, hv.z, a0); a0 = dot2(v0.w, hv.w, a0);
      a1 = dot2(v1.x, hv.x, a1); a1 = dot2(v1.y, hv.y, a1);
      a1 = dot2(v1.z, hv.z, a1); a1 = dot2(v1.w, hv.w, a1);
      a2 = dot2(v2.x, hv.x, a2); a2 = dot2(v2.y, hv.y, a2);
      a2 = dot2(v2.z, hv.z, a2); a2 = dot2(v2.w, hv.w, a2);
      a3 = dot2(v3.x, hv.x, a3); a3 = dot2(v3.y, hv.y, a3);
      a3 = dot2(v3.z, hv.z, a3); a3 = dot2(v3.w, hv.w, a3);
    }
    // combine K-halves (both lanes end with identical full sums)
    float gi = a0 + __shfl_xor(a0, 1) + x0;
    float gf = a1 + __shfl_xor(a1, 1) + x1;
    float gg = a2 + __shfl_xor(a2, 1) + x2;
    float go = a3 + __shfl_xor(a3, 1) + x3;
    c = sigm(gf) * c + sigm(gi) * fast_tanh(gg);
    float hv = sigm(go) * fast_tanh(c);
    if (!half) {
      hout[(size_t)(bm + t) * H_ + u] = hv;
      hbuf[(cur ^ 1) * 256 + u] = f16bits(hv);
    }
    __syncthreads();
  }
}

// =====================================================================
// K4: masked attention pooling + logits. One block per batch.
// =====================================================================
__global__ __launch_bounds__(256) void k4_attn(
    const int* __restrict__ lengths, const void* __restrict__ attn_w,
    const void* __restrict__ attn_b, const void* __restrict__ out_w,
    const void* __restrict__ out_b, const char* __restrict__ ws,
    void* __restrict__ out)
{
  __shared__ float aw[256];
  __shared__ float sc[128];
  __shared__ float at[256];
  __shared__ float red[256];

  const int tid = threadIdx.x;
  const int b = blockIdx.x;
  const int f32 = *(const int*)(ws + OFF_FLAG);
  const float* hout = (const float*)(ws + OFF_HOUT);
  const int bm = b * S_;

  aw[tid] = ldv(attn_w, tid, f32);
  __syncthreads();
  if (tid < 128) {
    const float* hp = hout + (size_t)(bm + tid) * H_;
    float acc = 0.f;
    for (int k = 0; k < 256; k += 4) {
      float4 h4 = *(const float4*)(hp + k);
      acc += h4.x * aw[k] + h4.y * aw[k + 1] + h4.z * aw[k + 2] + h4.w * aw[k + 3];
    }
    sc[tid] = acc + ldv(attn_b, 0, f32);
  }
  __syncthreads();
  if (tid == 0) {
    int len = lengths[b];
    float mx = -3.4e38f;
    for (int s = 0; s < len; ++s) mx = fmaxf(mx, sc[s]);
    float sum = 0.f;
    for (int s = 0; s < 128; ++s) {
      float v = (s < len) ? __expf(sc[s] - mx) : 0.f;
      sc[s] = v; sum += v;
    }
    float inv = 1.f / sum;
    for (int s = 0; s < 128; ++s) sc[s] *= inv;
  }
  __syncthreads();
  {
    float acc = 0.f;
    for (int s = 0; s < 128; ++s)
      acc += sc[s] * hout[(size_t)(bm + s) * H_ + tid];
    at[tid] = acc;
  }
  __syncthreads();
  for (int cc = 0; cc < 3; ++cc) {
    red[tid] = at[tid] * ldv(out_w, cc * 256 + tid, f32);
    __syncthreads();
    for (int off = 128; off > 0; off >>= 1) {
      if (tid < off) red[tid] += red[tid + off];
      __syncthreads();
    }
    if (tid == 0) {
      float v = red[0] + ldv(out_b, cc, f32);
      if (f32) ((float*)out)[b * 3 + cc] = v;
      else     ((ushort_t*)out)[b * 3 + cc] = f2b(v);
    }
    __syncthreads();
  }
}

// =====================================================================
extern "C" void kernel_launch(void* const* d_in, const int* in_sizes, int n_in,
                              void* d_out, int out_size, void* d_ws, size_t ws_size,
                              hipStream_t stream)
{
  const int* inputs  = (const int*)d_in[0];
  const int* triples = (const int*)d_in[2];
  const int* lengths = (const int*)d_in[3];
  const int* id2     = (const int*)d_in[4];
  const void* emb    = d_in[5];
  const void* ent    = d_in[6];
  const void* rel    = d_in[7];
  const void* W_ent  = d_in[8];
  const void* W_ih   = d_in[9];
  const void* W_hh   = d_in[10];
  const void* b_lstm = d_in[11];
  const void* attn_w = d_in[12];
  const void* attn_b = d_in[13];
  const void* out_w  = d_in[14];
  const void* out_b  = d_in[15];
  char* ws = (char*)d_ws;

  constexpr int K3_SMEM = 16 * 512 * 16 + 2 * 256 * 2;  // 132096 B
  static bool attr_set = false;
  if (!attr_set) {
    (void)hipFuncSetAttribute((const void*)k3_lstm,
                              hipFuncAttributeMaxDynamicSharedMemorySize, K3_SMEM);
    attr_set = true;
  }

  k_detect<<<dim3(1), dim3(64), 0, stream>>>((const uint_t*)emb, ws);
  k0_prep<<<dim3(2639), dim3(256), 0, stream>>>(W_ent, W_ih, W_hh, ws);
  k1_graph<<<dim3(M_), dim3(128), 0, stream>>>(inputs, triples, id2, emb, ent, rel, ws);
  k2_xg<<<dim3(64, 8), dim3(256), 0, stream>>>(b_lstm, ws);
  k3_lstm<<<dim3(B_), dim3(512), K3_SMEM, stream>>>(ws);
  k4_attn<<<dim3(B_), dim3(256), 0, stream>>>(lengths, attn_w, attn_b, out_w, out_b, ws, d_out);
}

// Round 4
// 525.996 us; speedup vs baseline: 1.2180x; 1.1387x over previous
//
#include <hip/hip_runtime.h>
#include <cstdint>
#include <cstddef>

typedef unsigned int  uint_t;
typedef unsigned short ushort_t;

// ---- shapes (fixed for this problem) ----
constexpr int B_  = 64;
constexpr int S_  = 128;
constexpr int D_  = 100;   // triple embedding dim
constexpr int E_  = 300;   // word embedding dim
constexpr int H_  = 256;   // hidden
constexpr int KIN = 512;   // LSTM input 500 padded to 512 for MFMA K
constexpr int NG  = 1024;  // 4*H gates
constexpr int M_  = B_ * S_;  // 8192

// K3 weight split: per gate row, each thread owns 64 f16x2 words (half of K);
// RW in VGPRs, LW in LDS.
constexpr int RW = 48;
constexpr int LW = 16;   // 4 chunks of 4 words

// ---- workspace layout (bytes) ----
constexpr size_t OFF_WT   = 0;                                  // W_ent^T packed f16x2 [100 kp][100 d] (40000 B)
constexpr size_t OFF_FLAG = 40000;                              // int: 1 if inputs are fp32, 0 if bf16
constexpr size_t OFF_WIH  = 40960;                              // W_ih padded bf16 [1024][512]
constexpr size_t OFF_WHH  = OFF_WIH + (size_t)NG * KIN * 2;     // W_hh as f16x2, [128][1024] u32
constexpr size_t OFF_TIN  = OFF_WHH + (size_t)128 * NG * 4;     // t_in bf16 [8192][512]
constexpr size_t OFF_XG   = OFF_TIN + (size_t)M_ * KIN * 2;     // xg f32 [8192][1024]
constexpr size_t OFF_HOUT = OFF_XG + (size_t)M_ * NG * 4;       // h f32 [8192][256]
// total ~50 MB

// ---- helpers ----
__device__ __forceinline__ float b2f(ushort_t u) {
  union { uint_t u; float f; } v; v.u = ((uint_t)u) << 16; return v.f;
}
__device__ __forceinline__ float blo(uint_t u) {
  union { uint_t u; float f; } v; v.u = u << 16; return v.f;
}
__device__ __forceinline__ float bhi(uint_t u) {
  union { uint_t u; float f; } v; v.u = u & 0xffff0000u; return v.f;
}
__device__ __forceinline__ ushort_t f2b(float f) {  // RNE float->bf16
  union { float f; uint_t u; } v; v.f = f;
  uint_t r = (v.u + 0x7fffu + ((v.u >> 16) & 1u)) >> 16;
  return (ushort_t)r;
}
__device__ __forceinline__ ushort_t f16bits(float f) {
  _Float16 h = (_Float16)f;
  union { _Float16 h; ushort_t u; } v; v.h = h; return v.u;
}
__device__ __forceinline__ uint_t pk16(float a, float b) {
  return (uint_t)f16bits(a) | ((uint_t)f16bits(b) << 16);
}
__device__ __forceinline__ float fast_tanh(float x) {
  float e = __expf(2.f * x);
  return 1.f - 2.f / (e + 1.f);
}
__device__ __forceinline__ float sigm(float x) {
  return 1.f / (1.f + __expf(-x));
}
// dtype-flexible load of an external "float" tensor
__device__ __forceinline__ float ldv(const void* p, size_t i, int f32) {
  return f32 ? ((const float*)p)[i] : b2f(((const ushort_t*)p)[i]);
}

#if defined(__has_builtin)
#if __has_builtin(__builtin_amdgcn_fdot2)
#define HAVE_FDOT2 1
#endif
#endif

typedef _Float16 half2v __attribute__((ext_vector_type(2)));

__device__ __forceinline__ float dot2(uint_t w, uint_t h, float acc) {
#ifdef HAVE_FDOT2
  union { uint_t u; half2v v; } a, b; a.u = w; b.u = h;
  return __builtin_amdgcn_fdot2(a.v, b.v, acc, false);
#else
  union { uint_t u; _Float16 h[2]; } a, b; a.u = w; b.u = h;
  acc += (float)a.h[0] * (float)b.h[0];
  acc += (float)a.h[1] * (float)b.h[1];
  return acc;
#endif
}

// =====================================================================
// K_detect: decide whether external float tensors are fp32 or bf16.
// =====================================================================
__global__ __launch_bounds__(64) void k_detect(const uint_t* __restrict__ emb_w,
                                               char* __restrict__ ws)
{
  int tid = threadIdx.x;
  int hits = 0;
  for (int i = 0; i < 8; ++i) {
    uint_t w = emb_w[i * 64 + tid];
    uint_t e = (w >> 7) & 0xffu;   // exponent field of lo-ushort-as-bf16
    hits += (e >= 140) ? 1 : 0;
  }
  for (int off = 32; off > 0; off >>= 1) hits += __shfl_down(hits, off);
  if (tid == 0) *(int*)(ws + OFF_FLAG) = (hits >= 32) ? 1 : 0;
}

// =====================================================================
// K0: weight prep. Wt = W_ent^T packed f16x2 (K-pairs); W_ih padded
// K 500->512 (bf16); W_hh -> f16x2 packed, transposed to [kpair][row].
// =====================================================================
__global__ __launch_bounds__(256) void k0_prep(
    const void* __restrict__ W_ent, const void* __restrict__ W_ih,
    const void* __restrict__ W_hh, char* __restrict__ ws)
{
  const int f32 = *(const int*)(ws + OFF_FLAG);
  int id = blockIdx.x * 256 + threadIdx.x;
  uint_t*   Wt = (uint_t*)(ws + OFF_WT);
  ushort_t* Wp = (ushort_t*)(ws + OFF_WIH);
  uint_t*   WT = (uint_t*)(ws + OFF_WHH);
  if (id < 10000) {
    // Wt[kp*100+d] = pack(f16(W_ent[d][2kp]), f16(W_ent[d][2kp+1]))
    int kp = id / 100, d = id % 100;
    float a = ldv(W_ent, (size_t)d * 200 + 2 * kp,     f32);
    float b = ldv(W_ent, (size_t)d * 200 + 2 * kp + 1, f32);
    Wt[id] = pk16(a, b);
  } else if (id >= 20000 && id < 20000 + NG * KIN) {
    int i = id - 20000;
    int n = i >> 9, k = i & 511;
    Wp[i] = (k < 500) ? f2b(ldv(W_ih, (size_t)n * 500 + k, f32)) : (ushort_t)0;
  } else if (id >= 20000 + NG * KIN && id < 20000 + NG * KIN + 128 * NG) {
    int i = id - 20000 - NG * KIN;
    int kk = i >> 10, j = i & 1023;
    ushort_t lo = f16bits(ldv(W_hh, (size_t)j * 256 + 2 * kk,     f32));
    ushort_t hi = f16bits(ldv(W_hh, (size_t)j * 256 + 2 * kk + 1, f32));
    WT[kk * 1024 + j] = (uint_t)lo | ((uint_t)hi << 16);
  }
}

// =====================================================================
// K1: triple graph attention; writes t_in bf16 [m][512].
// v2: 4 tokens per block, 512 threads (token slot j = tid>>7, local
// lt = tid&127). Wl2 (40 KB) staged ONCE per block and shared by the 4
// tokens -> Wt L2 traffic /4; LDS 72.8 KB -> 2 blocks/CU x 8 waves =
// 4 waves/SIMD (vs 1.5 before) for latency hiding of gathers + hot loop.
// Per-token code identical to v1 (packed f16x2 dot2 hot loop).
// =====================================================================
__global__ __launch_bounds__(512) void k1_graph(
    const int* __restrict__ inputs, const int* __restrict__ triples,
    const int* __restrict__ id2, const void* __restrict__ emb,
    const void* __restrict__ ent, const void* __restrict__ rel,
    char* __restrict__ ws)
{
  __shared__ __align__(16) uint_t Wl2[10000];    // packed f16x2 [kp][d], 40000 B
  __shared__ uint_t htp[4][10][100];             // packed f16x2 per token
  __shared__ float er_l[4][10][100];
  __shared__ float e_l[4][10];
  __shared__ float alpha_l[4][10];
  __shared__ int   trip_l[4][30];
  __shared__ int   vflag[4];

  const int tid = threadIdx.x;
  const int j   = tid >> 7;        // token slot 0..3
  const int lt  = tid & 127;       // local tid within token group
  const int m   = blockIdx.x * 4 + j;  // b*128+s
  const int f32 = *(const int*)(ws + OFF_FLAG);
  ushort_t* tin = (ushort_t*)(ws + OFF_TIN);

  if (lt < 30) trip_l[j][lt] = triples[(size_t)m * 30 + lt];
  if (lt == 0) vflag[j] = 0;
  if (lt < 10) e_l[j][lt] = 0.f;
  __syncthreads();
  if (lt < 10 && id2[(size_t)m * 10 + lt] != -1) atomicOr(&vflag[j], 1);

  {
    const uint4* src = (const uint4*)(ws + OFF_WT);
    uint4* dst = (uint4*)Wl2;
    for (int i = tid; i < 2500; i += 512) dst[i] = src[i];
  }
  // gather ht rows, pack to f16x2 pairs
  for (int i = lt; i < 1000; i += 128) {
    int t = i / 100, kp = i % 100;
    int row = trip_l[j][t * 3 + (kp < 50 ? 0 : 1)];
    int off = (kp < 50) ? 2 * kp : 2 * (kp - 50);
    float x0, x1;
    if (f32) {
      float2 v = *(const float2*)((const float*)ent + (size_t)row * 100 + off);
      x0 = v.x; x1 = v.y;
    } else {
      uint_t u = *(const uint_t*)((const ushort_t*)ent + (size_t)row * 100 + off);
      x0 = blo(u); x1 = bhi(u);
    }
    htp[j][t][kp] = pk16(x0, x1);
  }
  for (int i = lt; i < 1000; i += 128) {
    int t = i / 100, d = i % 100;
    er_l[j][t][d] = ldv(rel, (size_t)trip_l[j][t * 3 + 2] * 100 + d, f32);
  }
  {
    int w = inputs[m];
    for (int c = lt; c < 300; c += 128)
      tin[(size_t)m * KIN + c] = f2b(ldv(emb, (size_t)w * E_ + c, f32));
    if (lt < 12) tin[(size_t)m * KIN + 500 + lt] = 0;
  }
  __syncthreads();

  if (lt < 125) {
    int t2 = lt / 25, d4 = lt % 25;
    int t0 = 2 * t2, t1 = t0 + 1;
    const uint_t* h0p = htp[j][t0];
    const uint_t* h1p = htp[j][t1];
    float a00 = 0, a01 = 0, a02 = 0, a03 = 0;
    float a10 = 0, a11 = 0, a12 = 0, a13 = 0;
    for (int kp = 0; kp < 100; ++kp) {
      uint4 wv = *(const uint4*)&Wl2[kp * 100 + 4 * d4];  // 4 d-columns at this K-pair
      uint_t hp0 = h0p[kp], hp1 = h1p[kp];
      a00 = dot2(wv.x, hp0, a00); a01 = dot2(wv.y, hp0, a01);
      a02 = dot2(wv.z, hp0, a02); a03 = dot2(wv.w, hp0, a03);
      a10 = dot2(wv.x, hp1, a10); a11 = dot2(wv.y, hp1, a11);
      a12 = dot2(wv.z, hp1, a12); a13 = dot2(wv.w, hp1, a13);
    }
    int d = 4 * d4;
    float s0 = fast_tanh(a00) * er_l[j][t0][d]     + fast_tanh(a01) * er_l[j][t0][d + 1]
             + fast_tanh(a02) * er_l[j][t0][d + 2] + fast_tanh(a03) * er_l[j][t0][d + 3];
    float s1 = fast_tanh(a10) * er_l[j][t1][d]     + fast_tanh(a11) * er_l[j][t1][d + 1]
             + fast_tanh(a12) * er_l[j][t1][d + 2] + fast_tanh(a13) * er_l[j][t1][d + 3];
    atomicAdd(&e_l[j][t0], s0);
    atomicAdd(&e_l[j][t1], s1);
  }
  __syncthreads();
  if (lt == 0) {
    float mx = e_l[j][0];
    for (int t = 1; t < 10; ++t) mx = fmaxf(mx, e_l[j][t]);
    float s = 0.f;
    for (int t = 0; t < 10; ++t) { float v = __expf(e_l[j][t] - mx); alpha_l[j][t] = v; s += v; }
    float inv = 1.f / s;
    for (int t = 0; t < 10; ++t) alpha_l[j][t] *= inv;
  }
  __syncthreads();
  for (int kp = lt; kp < 100; kp += 128) {
    float g0 = 0.f, g1 = 0.f;
#pragma unroll
    for (int t = 0; t < 10; ++t) {
      union { uint_t u; _Float16 h[2]; } v; v.u = htp[j][t][kp];
      g0 += alpha_l[j][t] * (float)v.h[0];
      g1 += alpha_l[j][t] * (float)v.h[1];
    }
    if (!vflag[j]) { g0 = 0.f; g1 = 0.f; }
    tin[(size_t)m * KIN + 300 + 2 * kp]     = f2b(g0);
    tin[(size_t)m * KIN + 300 + 2 * kp + 1] = f2b(g1);
  }
}

// =====================================================================
// K2: xg = t_in @ W_ih^T + b.  MFMA 16x16x32 bf16, 128x128 tiles, BK=32.
// =====================================================================
typedef __attribute__((ext_vector_type(8))) short short8;
typedef __attribute__((ext_vector_type(4))) float f32x4;

__global__ __launch_bounds__(256) void k2_xg(
    const void* __restrict__ bl, char* __restrict__ ws)
{
  __shared__ __align__(16) ushort_t As[128 * 32];
  __shared__ __align__(16) ushort_t Bs[128 * 32];
  const ushort_t* A  = (const ushort_t*)(ws + OFF_TIN);
  const ushort_t* Bw = (const ushort_t*)(ws + OFF_WIH);
  float* xg = (float*)(ws + OFF_XG);
  const int f32 = *(const int*)(ws + OFF_FLAG);

  const int tid = threadIdx.x;
  const int m0 = blockIdx.x * 128;
  const int n0 = blockIdx.y * 128;
  const int lane = tid & 63, wv = tid >> 6;
  const int wm = wv & 1, wn = wv >> 1;
  const int g = lane >> 4, r = lane & 15;

  f32x4 acc[4][4] = {};

  for (int ks = 0; ks < 16; ++ks) {
    const int k0 = ks * 32;
    {
      int c0 = tid, c1 = tid + 256;
      uint4 a0 = *(const uint4*)(A  + (size_t)(m0 + (c0 >> 2)) * KIN + k0 + ((c0 & 3) << 3));
      uint4 a1 = *(const uint4*)(A  + (size_t)(m0 + (c1 >> 2)) * KIN + k0 + ((c1 & 3) << 3));
      uint4 b0 = *(const uint4*)(Bw + (size_t)(n0 + (c0 >> 2)) * KIN + k0 + ((c0 & 3) << 3));
      uint4 b1 = *(const uint4*)(Bw + (size_t)(n0 + (c1 >> 2)) * KIN + k0 + ((c1 & 3) << 3));
      ((uint4*)As)[c0] = a0; ((uint4*)As)[c1] = a1;
      ((uint4*)Bs)[c0] = b0; ((uint4*)Bs)[c1] = b1;
    }
    __syncthreads();
    short8 av[4], bv[4];
#pragma unroll
    for (int i = 0; i < 4; ++i)
      av[i] = *(const short8*)&As[(wm * 64 + i * 16 + r) * 32 + g * 8];
#pragma unroll
    for (int j = 0; j < 4; ++j)
      bv[j] = *(const short8*)&Bs[(wn * 64 + j * 16 + r) * 32 + g * 8];
#pragma unroll
    for (int i = 0; i < 4; ++i)
#pragma unroll
      for (int j = 0; j < 4; ++j)
        acc[i][j] = __builtin_amdgcn_mfma_f32_16x16x32_bf16(av[i], bv[j], acc[i][j], 0, 0, 0);
    __syncthreads();
  }
#pragma unroll
  for (int j = 0; j < 4; ++j) {
    int n = n0 + wn * 64 + j * 16 + r;
    float bias = ldv(bl, n, f32);
#pragma unroll
    for (int i = 0; i < 4; ++i) {
      int mrow = m0 + wm * 64 + i * 16 + g * 4;
#pragma unroll
      for (int rr = 0; rr < 4; ++rr)
        xg[(size_t)(mrow + rr) * NG + n] = acc[i][j][rr] + bias;
    }
  }
}

// =====================================================================
// K3: recurrent LSTM, hybrid reg+LDS weights, occupancy pinned.
// 64 blocks (1/batch) x 512 threads (8 waves = 2/SIMD, pinned via
// amdgpu_waves_per_eu(2,2) -> 256-VGPR budget the allocator can use).
// Thread-pair (lanes 2j,2j+1) owns hidden unit u=tid>>1, all 4 gate
// rows {u,u+256,u+512,u+768}; K split in halves across the pair
// (half=tid&1 -> words [64*half, 64*half+64)). Per row: RW=48 words in
// VGPRs (4x48=192 regs), LW=16 words in LDS ([chunk][tid] uint4,
// conflict-free b128). h double-buffered in LDS as f16x2; one barrier
// per step; xg software-prefetched one step ahead.
// =====================================================================
__global__ __attribute__((amdgpu_waves_per_eu(2, 2))) __launch_bounds__(512)
void k3_lstm(char* __restrict__ ws)
{
  extern __shared__ __align__(16) char smem[];
  uint4*    ldsw = (uint4*)smem;                          // [16][512] uint4 = 128 KB
  ushort_t* hbuf = (ushort_t*)(smem + 16 * 512 * 16);     // [2][256] f16

  const int tid  = threadIdx.x;
  const int b    = blockIdx.x;
  const int u    = tid >> 1;          // hidden unit 0..255
  const int half = tid & 1;           // K-half
  const int kbase = half * 64;        // first f16x2 word of my K-half

  const uint_t* WT = (const uint_t*)(ws + OFF_WHH);  // [kpair][1024]
  const float* xg = (const float*)(ws + OFF_XG);
  float* hout = (float*)(ws + OFF_HOUT);

  const int row0 = u, row1 = u + 256, row2 = u + 512, row3 = u + 768;

  // ---- register-resident weights: 4 rows x RW words
  uint_t w0[RW], w1[RW], w2[RW], w3[RW];
#pragma unroll
  for (int q = 0; q < RW; ++q) {
    w0[q] = WT[(size_t)(kbase + q) * 1024 + row0];
    w1[q] = WT[(size_t)(kbase + q) * 1024 + row1];
    w2[q] = WT[(size_t)(kbase + q) * 1024 + row2];
    w3[q] = WT[(size_t)(kbase + q) * 1024 + row3];
  }
  // ---- LDS-resident weights: chunk c=i*4+p holds words kbase+RW+4p..+3 of row i
  {
    const int rows[4] = { row0, row1, row2, row3 };
#pragma unroll
    for (int i = 0; i < 4; ++i)
#pragma unroll
      for (int p = 0; p < 4; ++p) {
        uint4 v;
        v.x = WT[(size_t)(kbase + RW + 4 * p + 0) * 1024 + rows[i]];
        v.y = WT[(size_t)(kbase + RW + 4 * p + 1) * 1024 + rows[i]];
        v.z = WT[(size_t)(kbase + RW + 4 * p + 2) * 1024 + rows[i]];
        v.w = WT[(size_t)(kbase + RW + 4 * p + 3) * 1024 + rows[i]];
        ldsw[(i * 4 + p) * 512 + tid] = v;
      }
  }
  hbuf[tid] = 0;   // zero both h buffers (512 f16 entries)
  float c = 0.f;
  __syncthreads();

  const int bm = b * S_;
  // prefetch xg for t=0
  const float* xp0 = xg + (size_t)bm * NG;
  float xn0 = xp0[row0], xn1 = xp0[row1], xn2 = xp0[row2], xn3 = xp0[row3];

  for (int t = 0; t < S_; ++t) {
    const int cur = t & 1;
    float x0 = xn0, x1 = xn1, x2 = xn2, x3 = xn3;
    if (t + 1 < S_) {   // prefetch next step's gate inputs
      const float* xq = xg + (size_t)(bm + t + 1) * NG;
      xn0 = xq[row0]; xn1 = xq[row1]; xn2 = xq[row2]; xn3 = xq[row3];
    }
    const uint_t* hb = (const uint_t*)(hbuf + cur * 256);
    float a0 = 0.f, a1 = 0.f, a2 = 0.f, a3 = 0.f;
    // register part: 12 uint4 h-reads x 16 dot2
#pragma unroll
    for (int qq = 0; qq < RW / 4; ++qq) {
      uint4 hv = *(const uint4*)&hb[kbase + 4 * qq];
      a0 = dot2(w0[4 * qq], hv.x, a0); a0 = dot2(w0[4 * qq + 1], hv.y, a0);
      a0 = dot2(w0[4 * qq + 2], hv.z, a0); a0 = dot2(w0[4 * qq + 3], hv.w, a0);
      a1 = dot2(w1[4 * qq], hv.x, a1); a1 = dot2(w1[4 * qq + 1], hv.y, a1);
      a1 = dot2(w1[4 * qq + 2], hv.z, a1); a1 = dot2(w1[4 * qq + 3], hv.w, a1);
      a2 = dot2(w2[4 * qq], hv.x, a2); a2 = dot2(w2[4 * qq + 1], hv.y, a2);
      a2 = dot2(w2[4 * qq + 2], hv.z, a2); a2 = dot2(w2[4 * qq + 3], hv.w, a2);
      a3 = dot2(w3[4 * qq], hv.x, a3); a3 = dot2(w3[4 * qq + 1], hv.y, a3);
      a3 = dot2(w3[4 * qq + 2], hv.z, a3); a3 = dot2(w3[4 * qq + 3], hv.w, a3);
    }
    // LDS part: words kbase+RW .. kbase+63
#pragma unroll
    for (int p = 0; p < 4; ++p) {
      uint4 hv = *(const uint4*)&hb[kbase + RW + 4 * p];
      uint4 v0 = ldsw[(0 * 4 + p) * 512 + tid];
      uint4 v1 = ldsw[(1 * 4 + p) * 512 + tid];
      uint4 v2 = ldsw[(2 * 4 + p) * 512 + tid];
      uint4 v3 = ldsw[(3 * 4 + p) * 512 + tid];
      a0 = dot2(v0.x, hv.x, a0); a0 = dot2(v0.y, hv.y, a0);
      a0 = dot2(v0.z, hv.z, a0); a0 = dot2(v0.w, hv.w, a0);
      a1 = dot2(v1.x, hv.x, a1); a1 = dot2(v1.y, hv.y, a1);
      a1 = dot2(v1.z, hv.z, a1); a1 = dot2(v1.w, hv.w, a1);
      a2 = dot2(v2.x, hv.x, a2); a2 = dot2(v2.y, hv.y, a2);
      a2 = dot2(v2.z, hv.z, a2); a2 = dot2(v2.w, hv.w, a2);
      a3 = dot2(v3.x, hv.x, a3); a3 = dot2(v3.y, hv.y, a3);
      a3 = dot2(v3.z, hv.z, a3); a3 = dot2(v3.w, hv.w, a3);
    }
    // combine K-halves (both lanes end with identical full sums)
    float gi = a0 + __shfl_xor(a0, 1) + x0;
    float gf = a1 + __shfl_xor(a1, 1) + x1;
    float gg = a2 + __shfl_xor(a2, 1) + x2;
    float go = a3 + __shfl_xor(a3, 1) + x3;
    c = sigm(gf) * c + sigm(gi) * fast_tanh(gg);
    float hv = sigm(go) * fast_tanh(c);
    if (!half) {
      hout[(size_t)(bm + t) * H_ + u] = hv;
      hbuf[(cur ^ 1) * 256 + u] = f16bits(hv);
    }
    __syncthreads();
  }
}

// =====================================================================
// K4: masked attention pooling + logits. One block per batch.
// =====================================================================
__global__ __launch_bounds__(256) void k4_attn(
    const int* __restrict__ lengths, const void* __restrict__ attn_w,
    const void* __restrict__ attn_b, const void* __restrict__ out_w,
    const void* __restrict__ out_b, const char* __restrict__ ws,
    void* __restrict__ out)
{
  __shared__ float aw[256];
  __shared__ float sc[128];
  __shared__ float at[256];
  __shared__ float red[256];

  const int tid = threadIdx.x;
  const int b = blockIdx.x;
  const int f32 = *(const int*)(ws + OFF_FLAG);
  const float* hout = (const float*)(ws + OFF_HOUT);
  const int bm = b * S_;

  aw[tid] = ldv(attn_w, tid, f32);
  __syncthreads();
  if (tid < 128) {
    const float* hp = hout + (size_t)(bm + tid) * H_;
    float acc = 0.f;
    for (int k = 0; k < 256; k += 4) {
      float4 h4 = *(const float4*)(hp + k);
      acc += h4.x * aw[k] + h4.y * aw[k + 1] + h4.z * aw[k + 2] + h4.w * aw[k + 3];
    }
    sc[tid] = acc + ldv(attn_b, 0, f32);
  }
  __syncthreads();
  if (tid == 0) {
    int len = lengths[b];
    float mx = -3.4e38f;
    for (int s = 0; s < len; ++s) mx = fmaxf(mx, sc[s]);
    float sum = 0.f;
    for (int s = 0; s < 128; ++s) {
      float v = (s < len) ? __expf(sc[s] - mx) : 0.f;
      sc[s] = v; sum += v;
    }
    float inv = 1.f / sum;
    for (int s = 0; s < 128; ++s) sc[s] *= inv;
  }
  __syncthreads();
  {
    float acc = 0.f;
    for (int s = 0; s < 128; ++s)
      acc += sc[s] * hout[(size_t)(bm + s) * H_ + tid];
    at[tid] = acc;
  }
  __syncthreads();
  for (int cc = 0; cc < 3; ++cc) {
    red[tid] = at[tid] * ldv(out_w, cc * 256 + tid, f32);
    __syncthreads();
    for (int off = 128; off > 0; off >>= 1) {
      if (tid < off) red[tid] += red[tid + off];
      __syncthreads();
    }
    if (tid == 0) {
      float v = red[0] + ldv(out_b, cc, f32);
      if (f32) ((float*)out)[b * 3 + cc] = v;
      else     ((ushort_t*)out)[b * 3 + cc] = f2b(v);
    }
    __syncthreads();
  }
}

// =====================================================================
extern "C" void kernel_launch(void* const* d_in, const int* in_sizes, int n_in,
                              void* d_out, int out_size, void* d_ws, size_t ws_size,
                              hipStream_t stream)
{
  const int* inputs  = (const int*)d_in[0];
  const int* triples = (const int*)d_in[2];
  const int* lengths = (const int*)d_in[3];
  const int* id2     = (const int*)d_in[4];
  const void* emb    = d_in[5];
  const void* ent    = d_in[6];
  const void* rel    = d_in[7];
  const void* W_ent  = d_in[8];
  const void* W_ih   = d_in[9];
  const void* W_hh   = d_in[10];
  const void* b_lstm = d_in[11];
  const void* attn_w = d_in[12];
  const void* attn_b = d_in[13];
  const void* out_w  = d_in[14];
  const void* out_b  = d_in[15];
  char* ws = (char*)d_ws;

  constexpr int K3_SMEM = 16 * 512 * 16 + 2 * 256 * 2;  // 132096 B
  static bool attr_set = false;
  if (!attr_set) {
    (void)hipFuncSetAttribute((const void*)k3_lstm,
                              hipFuncAttributeMaxDynamicSharedMemorySize, K3_SMEM);
    attr_set = true;
  }

  k_detect<<<dim3(1), dim3(64), 0, stream>>>((const uint_t*)emb, ws);
  k0_prep<<<dim3(2639), dim3(256), 0, stream>>>(W_ent, W_ih, W_hh, ws);
  k1_graph<<<dim3(M_ / 4), dim3(512), 0, stream>>>(inputs, triples, id2, emb, ent, rel, ws);
  k2_xg<<<dim3(64, 8), dim3(256), 0, stream>>>(b_lstm, ws);
  k3_lstm<<<dim3(B_), dim3(512), K3_SMEM, stream>>>(ws);
  k4_attn<<<dim3(B_), dim3(256), 0, stream>>>(lengths, attn_w, attn_b, out_w, out_b, ws, d_out);
}